// Round 4
// baseline (281.261 us; speedup 1.0000x reference)
//
#include <hip/hip_runtime.h>

#define B_ 8
#define N_ 4096
#define K_ 32
#define C_ 64
#define CIN_ 67
#define R2_ 0.0225f

#define SFJ 104   // s_fj row stride in shorts (208 B: 16B-aligned, 2-way banks)
#define SY1 72    // s_y1 row stride in shorts (144 B)
#define SFB 72    // s_vecbf / s_hbf row stride in shorts
#define PTS 4     // points per block-iteration
#define ITERS 4   // iterations per block (16 points per block)

typedef short short8v __attribute__((ext_vector_type(8)));
typedef short short4v __attribute__((ext_vector_type(4)));
typedef float floatx4 __attribute__((ext_vector_type(4)));

__device__ __forceinline__ short f2bf(float x) {
    unsigned u = __float_as_uint(x);
    u += 0x7fffu + ((u >> 16) & 1u);       // round-to-nearest-even
    return (short)(u >> 16);
}

// ---------------------------------------------------------------------------
// Prep: f[b][c][n] -> ftb[b][n][c] (bf16), p passthrough -> out, and packed
// p4[b][n] = (x,y,z,|p|^2). sq uses the same contract-off expression as the
// validated R1-R3 computation (bit-identical boundary decisions).
// ---------------------------------------------------------------------------
__global__ __launch_bounds__(256) void prep_kernel(
    const float* __restrict__ p, const float* __restrict__ f,
    unsigned short* __restrict__ ftb, float4* __restrict__ p4,
    float* __restrict__ pout)
{
#pragma clang fp contract(off)
    __shared__ short tile[64 * 72];
    const int t = threadIdx.x;
    const int b = blockIdx.x >> 6;
    const int n0 = (blockIdx.x & 63) * 64;
    const int nn4 = t & 15, ch = t >> 4;
    for (int cc = 0; cc < 4; ++cc) {
        const int c = cc * 16 + ch;
        const float4 v = *(const float4*)&f[((size_t)(b * 64 + c)) * N_ + n0 + nn4 * 4];
        tile[(nn4 * 4 + 0) * 72 + c] = f2bf(v.x);
        tile[(nn4 * 4 + 1) * 72 + c] = f2bf(v.y);
        tile[(nn4 * 4 + 2) * 72 + c] = f2bf(v.z);
        tile[(nn4 * 4 + 3) * 72 + c] = f2bf(v.w);
    }
    if (t < 48) {   // p passthrough (192 floats per block, 16B-aligned)
        const size_t base = ((size_t)(b * N_ + n0)) * 3;
        ((float4*)(pout + base))[t] = ((const float4*)(p + base))[t];
    }
    if (t < 64) {   // packed p4
        const int n = n0 + t;
        const float x = p[((size_t)(b * N_ + n)) * 3 + 0];
        const float y = p[((size_t)(b * N_ + n)) * 3 + 1];
        const float z = p[((size_t)(b * N_ + n)) * 3 + 2];
        const float sq = (x * x + y * y) + z * z;
        p4[(size_t)b * N_ + n] = make_float4(x, y, z, sq);
    }
    __syncthreads();
    const int nn = t >> 2, cb = (t & 3) * 16;
    uint4* dst = (uint4*)&ftb[((size_t)(b * N_ + n0 + nn)) * 64 + cb];
    const uint4* src = (const uint4*)&tile[nn * 72 + cb];
    dst[0] = src[0];
    dst[1] = src[1];
}

// ---------------------------------------------------------------------------
// Mega kernel: Phase A = in-block ball query (4 queries per wave, one shared
// candidate load per chunk), idx -> LDS. Phase B = MFMA attn/conv1/conv2 +
// softmax + MFMA FFN (R3-validated structure).
// ---------------------------------------------------------------------------
__global__ __launch_bounds__(256, 3) void lpa_mega_kernel(
    const float4* __restrict__ p4, const float* __restrict__ f,
    const unsigned short* __restrict__ ftb,
    const float* __restrict__ w_attn, const float* __restrict__ b_attn,
    const float* __restrict__ w1, const float* __restrict__ b1,
    const float* __restrict__ w2, const float* __restrict__ b2,
    const float* __restrict__ wf1, const float* __restrict__ bf1,
    const float* __restrict__ wf2, const float* __restrict__ bf2,
    float* __restrict__ out)
{
    __shared__ __align__(16) short s_fj[128 * SFJ];      // 26624 B
    __shared__ __align__(16) short s_y1[128 * SY1];      // 18432 B
    __shared__ __align__(16) short s_fbuf[2 * 16 * SFB]; // 4608 B
    __shared__ float s_vec[PTS * 64];                    // 1024 B
    __shared__ unsigned short s_idx[16 * K_];            // 1024 B
    short* s_vecbf = s_fbuf;
    short* s_hbf   = s_fbuf + 16 * SFB;

    const int t = threadIdx.x;
    const int lane = t & 63;
    const int mb = t >> 6;
    const int l15 = lane & 15;
    const int quad = lane >> 4;

    const int blk_pt0 = blockIdx.x * (PTS * ITERS);
    const int bb = blk_pt0 >> 12;                 // batch (16 divides 4096)
    const float4* pb = p4 + (size_t)bb * N_;

    // zero fj pad region i'=[72,104) and the ffn staging buffers (read after
    // bar1/bar3 of iter 0 -> barA + bar1 order them correctly)
    for (int e = t; e < 512; e += 256) {
        const int col = e >> 2, c4 = e & 3;
        *(uint4*)&s_fj[col * SFJ + 72 + c4 * 8] = make_uint4(0u, 0u, 0u, 0u);
    }
    for (int e = t; e < 1152; e += 256) ((unsigned*)s_fbuf)[e] = 0u;

    // ---- Phase A: ball query, wave mb owns points mb*4 .. mb*4+3 ----
    {
#pragma clang fp contract(off)
        float4 Q[4];
        #pragma unroll
        for (int q = 0; q < 4; ++q)
            Q[q] = pb[(blk_pt0 + mb * 4 + q) & (N_ - 1)];
        int count[4] = {0, 0, 0, 0};
        int first[4] = {-1, -1, -1, -1};
        for (int base = 0; base < N_; base += 64) {
            const float4 A = pb[base + lane];
            unsigned long long m[4];
            bool w[4];
            #pragma unroll
            for (int q = 0; q < 4; ++q) {
                const float d2 = (Q[q].w + A.w)
                    - 2.0f * ((Q[q].x * A.x + Q[q].y * A.y) + Q[q].z * A.z);
                w[q] = (d2 <= R2_);
                m[q] = __ballot(w[q]);
            }
            const unsigned long long below = (1ull << lane) - 1ull;
            #pragma unroll
            for (int q = 0; q < 4; ++q) {
                if (m[q]) {
                    if (first[q] < 0) first[q] = base + __builtin_ctzll(m[q]);
                    if (w[q]) {
                        const int pos = count[q] + __popcll(m[q] & below);
                        if (pos < K_)
                            s_idx[(mb * 4 + q) * K_ + pos] = (unsigned short)(base + lane);
                    }
                    count[q] += __popcll(m[q]);
                }
            }
            if (count[0] >= K_ && count[1] >= K_ && count[2] >= K_ && count[3] >= K_)
                break;
        }
        #pragma unroll
        for (int q = 0; q < 4; ++q)
            for (int pos = count[q] + lane; pos < K_; pos += 64)
                s_idx[(mb * 4 + q) * K_ + pos] = (unsigned short)first[q];
    }

    // ---- weight A-fragments in registers (once per block) ----
    short8v wa_f[3], w1_f[3], w2_f[2], wf1_f[2], wf2_f[2];
    {
        const int cm = mb * 16 + l15;
        #pragma unroll
        for (int ks = 0; ks < 3; ++ks) {
            short8v a, bq;
            #pragma unroll
            for (int j = 0; j < 8; ++j) {
                const int ip = ks * 32 + quad * 8 + j;   // permuted i'
                float va = 0.0f, vb = 0.0f;
                if (ip < 64)      { va = w_attn[cm * CIN_ + ip + 3];  vb = w1[cm * CIN_ + ip + 3]; }
                else if (ip < 67) { va = w_attn[cm * CIN_ + ip - 64]; vb = w1[cm * CIN_ + ip - 64]; }
                a[j] = f2bf(va); bq[j] = f2bf(vb);
            }
            wa_f[ks] = a; w1_f[ks] = bq;
        }
        #pragma unroll
        for (int ks = 0; ks < 2; ++ks) {
            short8v a, bq, cq;
            #pragma unroll
            for (int j = 0; j < 8; ++j) {
                const int kk = ks * 32 + quad * 8 + j;
                a[j]  = f2bf(w2[cm * 64 + kk]);
                bq[j] = f2bf(wf1[cm * 64 + kk]);
                cq[j] = f2bf(wf2[cm * 64 + kk]);
            }
            w2_f[ks] = a; wf1_f[ks] = bq; wf2_f[ks] = cq;
        }
    }

    const int crow = mb * 16 + quad * 4;          // C/D row base (channel)
    const float4 bav  = *(const float4*)&b_attn[crow];
    const float4 b1v  = *(const float4*)&b1[crow];
    const float4 b2v  = *(const float4*)&b2[crow];
    const float4 bf1v = *(const float4*)&bf1[crow];
    const float4 bf2v = *(const float4*)&bf2[crow];

    __syncthreads();   // barA: s_idx (and pads) ready for all waves

    for (int itn = 0; itn < ITERS; ++itn) {
        const int pt0 = blk_pt0 + itn * PTS;

        // ---- gather: 2 threads per column, idx from LDS ----
        {
            const int col = t >> 1, h = t & 1;
            const int j = s_idx[itn * 128 + col];
            const uint4* src = (const uint4*)&ftb[((size_t)(bb * N_ + j)) * 64 + h * 32];
            uint4* dst = (uint4*)&s_fj[col * SFJ + h * 32];
            dst[0] = src[0]; dst[1] = src[1]; dst[2] = src[2]; dst[3] = src[3];
            if (h) {
                const int n = (pt0 + (col >> 5)) & (N_ - 1);
                const float4 Pj = pb[j];
                const float4 Pn = pb[n];
                short8v dp = {};
                dp[0] = f2bf(Pj.x - Pn.x);
                dp[1] = f2bf(Pj.y - Pn.y);
                dp[2] = f2bf(Pj.z - Pn.z);
                *(short8v*)&s_fj[col * SFJ + 64] = dp;   // i' 64..71 (dp + zeros)
            }
        }
        __syncthreads();   // bar1: fj ready

        // ---- attn + conv1 MFMAs (shared B-frags); y1 -> LDS ----
        floatx4 accA[8];
        #pragma unroll
        for (int nt = 0; nt < 8; ++nt) {
            const short* bp = &s_fj[(nt * 16 + l15) * SFJ + quad * 8];
            const short8v fb0 = *(const short8v*)(bp);
            const short8v fb1 = *(const short8v*)(bp + 32);
            const short8v fb2 = *(const short8v*)(bp + 64);
            floatx4 a = {0.f, 0.f, 0.f, 0.f};
            a = __builtin_amdgcn_mfma_f32_16x16x32_bf16(wa_f[0], fb0, a, 0, 0, 0);
            a = __builtin_amdgcn_mfma_f32_16x16x32_bf16(wa_f[1], fb1, a, 0, 0, 0);
            a = __builtin_amdgcn_mfma_f32_16x16x32_bf16(wa_f[2], fb2, a, 0, 0, 0);
            accA[nt] = a;
            floatx4 y = {0.f, 0.f, 0.f, 0.f};
            y = __builtin_amdgcn_mfma_f32_16x16x32_bf16(w1_f[0], fb0, y, 0, 0, 0);
            y = __builtin_amdgcn_mfma_f32_16x16x32_bf16(w1_f[1], fb1, y, 0, 0, 0);
            y = __builtin_amdgcn_mfma_f32_16x16x32_bf16(w1_f[2], fb2, y, 0, 0, 0);
            short4v yp;
            yp[0] = f2bf(fmaxf(y[0] + b1v.x, 0.f));
            yp[1] = f2bf(fmaxf(y[1] + b1v.y, 0.f));
            yp[2] = f2bf(fmaxf(y[2] + b1v.z, 0.f));
            yp[3] = f2bf(fmaxf(y[3] + b1v.w, 0.f));
            *(short4v*)&s_y1[(nt * 16 + l15) * SY1 + crow] = yp;
        }
        __syncthreads();   // bar2: y1 ready

        // ---- conv2 MFMAs ----
        floatx4 accX[8];
        #pragma unroll
        for (int nt = 0; nt < 8; ++nt) {
            const short* bp = &s_y1[(nt * 16 + l15) * SY1 + quad * 8];
            const short8v yb0 = *(const short8v*)(bp);
            const short8v yb1 = *(const short8v*)(bp + 32);
            floatx4 x = {0.f, 0.f, 0.f, 0.f};
            x = __builtin_amdgcn_mfma_f32_16x16x32_bf16(w2_f[0], yb0, x, 0, 0, 0);
            x = __builtin_amdgcn_mfma_f32_16x16x32_bf16(w2_f[1], yb1, x, 0, 0, 0);
            accX[nt] = x;
        }

        // ---- softmax over K=32 (no max-sub; args bounded ~|2.5|) ----
        #pragma unroll
        for (int pi = 0; pi < PTS; ++pi) {
            const int n = (pt0 + pi) & (N_ - 1);
            float fo[4];
            #pragma unroll
            for (int r = 0; r < 4; ++r) {
                const float ba = (r == 0) ? bav.x : (r == 1) ? bav.y : (r == 2) ? bav.z : bav.w;
                const float bx = (r == 0) ? b2v.x : (r == 1) ? b2v.y : (r == 2) ? b2v.z : b2v.w;
                const float va = accA[2 * pi][r] + ba;
                const float vb = accA[2 * pi + 1][r] + ba;
                const float e0 = __expf(va);
                const float e1 = __expf(vb);
                float se = e0 + e1;
                float sw = e0 * (accX[2 * pi][r] + bx) + e1 * (accX[2 * pi + 1][r] + bx);
                se += __shfl_xor(se, 1); sw += __shfl_xor(sw, 1);
                se += __shfl_xor(se, 2); sw += __shfl_xor(sw, 2);
                se += __shfl_xor(se, 4); sw += __shfl_xor(sw, 4);
                se += __shfl_xor(se, 8); sw += __shfl_xor(sw, 8);
                const float fres = f[((size_t)(bb * 64 + crow + r)) * N_ + n];
                fo[r] = fmaxf(sw * __builtin_amdgcn_rcpf(se) + fres, 0.f);
            }
            if (l15 == 0) {
                *(float4*)&s_vec[pi * 64 + crow] = make_float4(fo[0], fo[1], fo[2], fo[3]);
                short4v fb;
                fb[0] = f2bf(fo[0]); fb[1] = f2bf(fo[1]);
                fb[2] = f2bf(fo[2]); fb[3] = f2bf(fo[3]);
                *(short4v*)&s_vecbf[pi * SFB + crow] = fb;
            }
        }
        __syncthreads();   // bar3: fout ready

        // ---- FFN layer 1 via MFMA: M=16 (wave ch), K=64, N=16 (4 used) ----
        {
            const short8v vb0 = *(const short8v*)&s_vecbf[l15 * SFB + quad * 8];
            const short8v vb1 = *(const short8v*)&s_vecbf[l15 * SFB + 32 + quad * 8];
            floatx4 d = {0.f, 0.f, 0.f, 0.f};
            d = __builtin_amdgcn_mfma_f32_16x16x32_bf16(wf1_f[0], vb0, d, 0, 0, 0);
            d = __builtin_amdgcn_mfma_f32_16x16x32_bf16(wf1_f[1], vb1, d, 0, 0, 0);
            if (l15 < PTS) {
                short4v hb;
                hb[0] = f2bf(fmaxf(d[0] + bf1v.x, 0.f));
                hb[1] = f2bf(fmaxf(d[1] + bf1v.y, 0.f));
                hb[2] = f2bf(fmaxf(d[2] + bf1v.z, 0.f));
                hb[3] = f2bf(fmaxf(d[3] + bf1v.w, 0.f));
                *(short4v*)&s_hbf[l15 * SFB + crow] = hb;
            }
        }
        __syncthreads();   // bar4: h ready

        // ---- FFN layer 2 via MFMA + residual + relu, store ----
        {
            const short8v hb0 = *(const short8v*)&s_hbf[l15 * SFB + quad * 8];
            const short8v hb1 = *(const short8v*)&s_hbf[l15 * SFB + 32 + quad * 8];
            floatx4 d = {0.f, 0.f, 0.f, 0.f};
            d = __builtin_amdgcn_mfma_f32_16x16x32_bf16(wf2_f[0], hb0, d, 0, 0, 0);
            d = __builtin_amdgcn_mfma_f32_16x16x32_bf16(wf2_f[1], hb1, d, 0, 0, 0);
            if (l15 < PTS) {
                const int n = (pt0 + l15) & (N_ - 1);
                out[((size_t)(bb * 64 + crow + 0)) * N_ + n] =
                    fmaxf(d[0] + bf2v.x + s_vec[l15 * 64 + crow + 0], 0.f);
                out[((size_t)(bb * 64 + crow + 1)) * N_ + n] =
                    fmaxf(d[1] + bf2v.y + s_vec[l15 * 64 + crow + 1], 0.f);
                out[((size_t)(bb * 64 + crow + 2)) * N_ + n] =
                    fmaxf(d[2] + bf2v.z + s_vec[l15 * 64 + crow + 2], 0.f);
                out[((size_t)(bb * 64 + crow + 3)) * N_ + n] =
                    fmaxf(d[3] + bf2v.w + s_vec[l15 * 64 + crow + 3], 0.f);
            }
        }
        // hazard audit: next gather's s_fj writes separated from this iter's
        // s_fj reads by bar2..bar4; s_vecbf rewrite (next softmax) is after
        // next bar2 > this FFN1 reads; s_hbf rewrite after next bar3 > this
        // FFN2 reads; s_idx is read-only after barA. No trailing barrier.
    }
}

extern "C" void kernel_launch(void* const* d_in, const int* in_sizes, int n_in,
                              void* d_out, int out_size, void* d_ws, size_t ws_size,
                              hipStream_t stream)
{
    const float* p      = (const float*)d_in[0];
    const float* f      = (const float*)d_in[1];
    const float* w_attn = (const float*)d_in[2];
    const float* b_attn = (const float*)d_in[3];
    const float* w1     = (const float*)d_in[4];
    const float* b1     = (const float*)d_in[5];
    const float* w2     = (const float*)d_in[6];
    const float* b2     = (const float*)d_in[7];
    const float* wf1    = (const float*)d_in[8];
    const float* bf1    = (const float*)d_in[9];
    const float* wf2    = (const float*)d_in[10];
    const float* bf2    = (const float*)d_in[11];
    float* out = (float*)d_out;

    unsigned short* ftb = (unsigned short*)d_ws;                        // 4 MB
    float4* p4          = (float4*)((char*)d_ws + 4u * 1024 * 1024);    // 512 KB

    prep_kernel<<<B_ * (N_ / 64), 256, 0, stream>>>(p, f, ftb, p4, out);
    lpa_mega_kernel<<<(B_ * N_) / (PTS * ITERS), 256, 0, stream>>>(
        p4, f, ftb, w_attn, b_attn, w1, b1, w2, b2, wf1, bf1, wf2, bf2,
        out + (size_t)B_ * N_ * 3);
}

// Round 5
// 229.202 us; speedup vs baseline: 1.2271x; 1.2271x over previous
//
#include <hip/hip_runtime.h>

#define B_ 8
#define N_ 4096
#define K_ 32
#define C_ 64
#define CIN_ 67
#define R2_ 0.0225f

#define SFJ 104   // s_fj row stride in shorts (208 B: 16B-aligned, 2-way banks)
#define SY1 72    // s_y1 row stride in shorts (144 B)
#define SFB 72    // s_vecbf / s_hbf row stride in shorts
#define PTS 4     // points per block-iteration
#define ITERS 4   // iterations per block (16 points per block)

typedef short short8v __attribute__((ext_vector_type(8)));
typedef short short4v __attribute__((ext_vector_type(4)));
typedef float floatx4 __attribute__((ext_vector_type(4)));

__device__ __forceinline__ short f2bf(float x) {
    unsigned u = __float_as_uint(x);
    u += 0x7fffu + ((u >> 16) & 1u);       // round-to-nearest-even
    return (short)(u >> 16);
}

// 16-lane sum via DPP (VALU pipe, not LDS): xor1, xor2, half-mirror, mirror.
template <int CTRL>
__device__ __forceinline__ float dpp_add(float x) {
    const int m = __builtin_amdgcn_update_dpp(0, __float_as_int(x), CTRL, 0xF, 0xF, false);
    return x + __int_as_float(m);
}
__device__ __forceinline__ float row16_sum(float x) {
    x = dpp_add<0xB1>(x);    // quad_perm(1,0,3,2)  : xor1
    x = dpp_add<0x4E>(x);    // quad_perm(2,3,0,1)  : xor2
    x = dpp_add<0x141>(x);   // row_half_mirror     : 8-groups combine
    x = dpp_add<0x140>(x);   // row_mirror          : halves combine
    return x;
}

// ---------------------------------------------------------------------------
// Prep: f[b][c][n] -> ftb[b][n][c] (bf16), p passthrough -> out, and packed
// p4[b][n] = (x,y,z,|p|^2). sq uses the validated contract-off expression.
// ---------------------------------------------------------------------------
__global__ __launch_bounds__(256) void prep_kernel(
    const float* __restrict__ p, const float* __restrict__ f,
    unsigned short* __restrict__ ftb, float4* __restrict__ p4,
    float* __restrict__ pout)
{
#pragma clang fp contract(off)
    __shared__ short tile[64 * 72];
    const int t = threadIdx.x;
    const int b = blockIdx.x >> 6;
    const int n0 = (blockIdx.x & 63) * 64;
    const int nn4 = t & 15, ch = t >> 4;
    for (int cc = 0; cc < 4; ++cc) {
        const int c = cc * 16 + ch;
        const float4 v = *(const float4*)&f[((size_t)(b * 64 + c)) * N_ + n0 + nn4 * 4];
        tile[(nn4 * 4 + 0) * 72 + c] = f2bf(v.x);
        tile[(nn4 * 4 + 1) * 72 + c] = f2bf(v.y);
        tile[(nn4 * 4 + 2) * 72 + c] = f2bf(v.z);
        tile[(nn4 * 4 + 3) * 72 + c] = f2bf(v.w);
    }
    if (t < 48) {   // p passthrough (192 floats per block, 16B-aligned)
        const size_t base = ((size_t)(b * N_ + n0)) * 3;
        ((float4*)(pout + base))[t] = ((const float4*)(p + base))[t];
    }
    if (t < 64) {   // packed p4
        const int n = n0 + t;
        const float x = p[((size_t)(b * N_ + n)) * 3 + 0];
        const float y = p[((size_t)(b * N_ + n)) * 3 + 1];
        const float z = p[((size_t)(b * N_ + n)) * 3 + 2];
        const float sq = (x * x + y * y) + z * z;
        p4[(size_t)b * N_ + n] = make_float4(x, y, z, sq);
    }
    __syncthreads();
    const int nn = t >> 2, cb = (t & 3) * 16;
    uint4* dst = (uint4*)&ftb[((size_t)(b * N_ + n0 + nn)) * 64 + cb];
    const uint4* src = (const uint4*)&tile[nn * 72 + cb];
    dst[0] = src[0];
    dst[1] = src[1];
}

// ---------------------------------------------------------------------------
// Ball query, 4 queries per wave (one shared candidate load per chunk),
// standalone for full occupancy (8 waves/SIMD hides L2 latency).
// Logic identical to R4 phase A (validated); output ushort idx to global.
// ---------------------------------------------------------------------------
__global__ __launch_bounds__(256) void ball_query_kernel(
    const float4* __restrict__ p4, unsigned short* __restrict__ idx)
{
#pragma clang fp contract(off)
    const int lane = threadIdx.x & 63;
    const int wid = (blockIdx.x * blockDim.x + threadIdx.x) >> 6;
    const int q0 = wid * 4;
    const int b = q0 >> 12;
    const float4* pb = p4 + (size_t)b * N_;

    float4 Q[4];
    #pragma unroll
    for (int q = 0; q < 4; ++q)
        Q[q] = pb[(q0 + q) & (N_ - 1)];
    int count[4] = {0, 0, 0, 0};
    int first[4] = {-1, -1, -1, -1};
    for (int base = 0; base < N_; base += 64) {
        const float4 A = pb[base + lane];
        unsigned long long m[4];
        bool w[4];
        #pragma unroll
        for (int q = 0; q < 4; ++q) {
            const float d2 = (Q[q].w + A.w)
                - 2.0f * ((Q[q].x * A.x + Q[q].y * A.y) + Q[q].z * A.z);
            w[q] = (d2 <= R2_);
            m[q] = __ballot(w[q]);
        }
        const unsigned long long below = (1ull << lane) - 1ull;
        #pragma unroll
        for (int q = 0; q < 4; ++q) {
            if (m[q]) {
                if (first[q] < 0) first[q] = base + __builtin_ctzll(m[q]);
                if (w[q]) {
                    const int pos = count[q] + __popcll(m[q] & below);
                    if (pos < K_)
                        idx[(size_t)(q0 + q) * K_ + pos] = (unsigned short)(base + lane);
                }
                count[q] += __popcll(m[q]);
            }
        }
        if (count[0] >= K_ && count[1] >= K_ && count[2] >= K_ && count[3] >= K_)
            break;
    }
    #pragma unroll
    for (int q = 0; q < 4; ++q)
        for (int pos = count[q] + lane; pos < K_; pos += 64)
            idx[(size_t)(q0 + q) * K_ + pos] = (unsigned short)first[q];
}

// ---------------------------------------------------------------------------
// Fused MFMA kernel (R3-validated structure). Block = 4 waves; wave mb owns
// channels [mb*16, mb*16+16). Per iter: 4 points = 8 N-tiles. attn/conv1/
// conv2 + FFN1/FFN2 all MFMA; softmax reductions via DPP (VALU pipe).
// ---------------------------------------------------------------------------
__global__ __launch_bounds__(256, 3) void lpa_mfma_kernel(
    const float4* __restrict__ p4, const float* __restrict__ f,
    const unsigned short* __restrict__ ftb,
    const float* __restrict__ w_attn, const float* __restrict__ b_attn,
    const float* __restrict__ w1, const float* __restrict__ b1,
    const float* __restrict__ w2, const float* __restrict__ b2,
    const float* __restrict__ wf1, const float* __restrict__ bf1,
    const float* __restrict__ wf2, const float* __restrict__ bf2,
    const unsigned short* __restrict__ idx, float* __restrict__ out)
{
    __shared__ __align__(16) short s_fj[128 * SFJ];      // 26624 B
    __shared__ __align__(16) short s_y1[128 * SY1];      // 18432 B
    __shared__ __align__(16) short s_fbuf[2 * 16 * SFB]; // 4608 B
    __shared__ float s_vec[PTS * 64];                    // 1024 B
    short* s_vecbf = s_fbuf;
    short* s_hbf   = s_fbuf + 16 * SFB;

    const int t = threadIdx.x;
    const int lane = t & 63;
    const int mb = t >> 6;
    const int l15 = lane & 15;
    const int quad = lane >> 4;

    // ---- weight A-fragments in registers (once per block) ----
    short8v wa_f[3], w1_f[3], w2_f[2], wf1_f[2], wf2_f[2];
    {
        const int cm = mb * 16 + l15;
        #pragma unroll
        for (int ks = 0; ks < 3; ++ks) {
            short8v a, bq;
            #pragma unroll
            for (int j = 0; j < 8; ++j) {
                const int ip = ks * 32 + quad * 8 + j;   // permuted i'
                float va = 0.0f, vb = 0.0f;
                if (ip < 64)      { va = w_attn[cm * CIN_ + ip + 3];  vb = w1[cm * CIN_ + ip + 3]; }
                else if (ip < 67) { va = w_attn[cm * CIN_ + ip - 64]; vb = w1[cm * CIN_ + ip - 64]; }
                a[j] = f2bf(va); bq[j] = f2bf(vb);
            }
            wa_f[ks] = a; w1_f[ks] = bq;
        }
        #pragma unroll
        for (int ks = 0; ks < 2; ++ks) {
            short8v a, bq, cq;
            #pragma unroll
            for (int j = 0; j < 8; ++j) {
                const int kk = ks * 32 + quad * 8 + j;
                a[j]  = f2bf(w2[cm * 64 + kk]);
                bq[j] = f2bf(wf1[cm * 64 + kk]);
                cq[j] = f2bf(wf2[cm * 64 + kk]);
            }
            w2_f[ks] = a; wf1_f[ks] = bq; wf2_f[ks] = cq;
        }
    }

    const int crow = mb * 16 + quad * 4;          // C/D row base (channel)
    const float4 bav  = *(const float4*)&b_attn[crow];
    const float4 b1v  = *(const float4*)&b1[crow];
    const float4 b2v  = *(const float4*)&b2[crow];
    const float4 bf1v = *(const float4*)&bf1[crow];
    const float4 bf2v = *(const float4*)&bf2[crow];

    // zero fj pad region i'=[72,104) and the ffn staging buffers
    for (int e = t; e < 512; e += 256) {
        const int col = e >> 2, c4 = e & 3;
        *(uint4*)&s_fj[col * SFJ + 72 + c4 * 8] = make_uint4(0u, 0u, 0u, 0u);
    }
    for (int e = t; e < 1152; e += 256) ((unsigned*)s_fbuf)[e] = 0u;

    const int pt00 = blockIdx.x * (PTS * ITERS);
    const int bb = pt00 >> 12;
    const float4* pb = p4 + (size_t)bb * N_;

    for (int itn = 0; itn < ITERS; ++itn) {
        const int pt0 = pt00 + itn * PTS;

        // ---- gather: 2 threads per column ----
        {
            const int col = t >> 1, h = t & 1;
            const int j = idx[(size_t)pt0 * K_ + col];
            const uint4* src = (const uint4*)&ftb[((size_t)(bb * N_ + j)) * 64 + h * 32];
            uint4* dst = (uint4*)&s_fj[col * SFJ + h * 32];
            dst[0] = src[0]; dst[1] = src[1]; dst[2] = src[2]; dst[3] = src[3];
            if (h) {
                const int n = (pt0 + (col >> 5)) & (N_ - 1);
                const float4 Pj = pb[j];
                const float4 Pn = pb[n];
                short8v dp = {};
                dp[0] = f2bf(Pj.x - Pn.x);
                dp[1] = f2bf(Pj.y - Pn.y);
                dp[2] = f2bf(Pj.z - Pn.z);
                *(short8v*)&s_fj[col * SFJ + 64] = dp;   // i' 64..71 (dp + zeros)
            }
        }
        __syncthreads();   // bar1: fj ready

        // ---- attn + conv1 MFMAs (shared B-frags); y1 -> LDS ----
        floatx4 accA[8];
        #pragma unroll
        for (int nt = 0; nt < 8; ++nt) {
            const short* bp = &s_fj[(nt * 16 + l15) * SFJ + quad * 8];
            const short8v fb0 = *(const short8v*)(bp);
            const short8v fb1 = *(const short8v*)(bp + 32);
            const short8v fb2 = *(const short8v*)(bp + 64);
            floatx4 a = {0.f, 0.f, 0.f, 0.f};
            a = __builtin_amdgcn_mfma_f32_16x16x32_bf16(wa_f[0], fb0, a, 0, 0, 0);
            a = __builtin_amdgcn_mfma_f32_16x16x32_bf16(wa_f[1], fb1, a, 0, 0, 0);
            a = __builtin_amdgcn_mfma_f32_16x16x32_bf16(wa_f[2], fb2, a, 0, 0, 0);
            accA[nt] = a;
            floatx4 y = {0.f, 0.f, 0.f, 0.f};
            y = __builtin_amdgcn_mfma_f32_16x16x32_bf16(w1_f[0], fb0, y, 0, 0, 0);
            y = __builtin_amdgcn_mfma_f32_16x16x32_bf16(w1_f[1], fb1, y, 0, 0, 0);
            y = __builtin_amdgcn_mfma_f32_16x16x32_bf16(w1_f[2], fb2, y, 0, 0, 0);
            short4v yp;
            yp[0] = f2bf(fmaxf(y[0] + b1v.x, 0.f));
            yp[1] = f2bf(fmaxf(y[1] + b1v.y, 0.f));
            yp[2] = f2bf(fmaxf(y[2] + b1v.z, 0.f));
            yp[3] = f2bf(fmaxf(y[3] + b1v.w, 0.f));
            *(short4v*)&s_y1[(nt * 16 + l15) * SY1 + crow] = yp;
        }
        __syncthreads();   // bar2: y1 ready

        // ---- conv2 MFMAs ----
        floatx4 accX[8];
        #pragma unroll
        for (int nt = 0; nt < 8; ++nt) {
            const short* bp = &s_y1[(nt * 16 + l15) * SY1 + quad * 8];
            const short8v yb0 = *(const short8v*)(bp);
            const short8v yb1 = *(const short8v*)(bp + 32);
            floatx4 x = {0.f, 0.f, 0.f, 0.f};
            x = __builtin_amdgcn_mfma_f32_16x16x32_bf16(w2_f[0], yb0, x, 0, 0, 0);
            x = __builtin_amdgcn_mfma_f32_16x16x32_bf16(w2_f[1], yb1, x, 0, 0, 0);
            accX[nt] = x;
        }

        // ---- softmax over K=32 (no max-sub; DPP reductions on VALU pipe) --
        #pragma unroll
        for (int pi = 0; pi < PTS; ++pi) {
            const int n = (pt0 + pi) & (N_ - 1);
            float fo[4];
            #pragma unroll
            for (int r = 0; r < 4; ++r) {
                const float ba = (r == 0) ? bav.x : (r == 1) ? bav.y : (r == 2) ? bav.z : bav.w;
                const float bx = (r == 0) ? b2v.x : (r == 1) ? b2v.y : (r == 2) ? b2v.z : b2v.w;
                const float e0 = __expf(accA[2 * pi][r] + ba);
                const float e1 = __expf(accA[2 * pi + 1][r] + ba);
                const float se = row16_sum(e0 + e1);
                const float sw = row16_sum(e0 * (accX[2 * pi][r] + bx)
                                         + e1 * (accX[2 * pi + 1][r] + bx));
                const float fres = f[((size_t)(bb * 64 + crow + r)) * N_ + n];
                fo[r] = fmaxf(sw * __builtin_amdgcn_rcpf(se) + fres, 0.f);
            }
            if (l15 == 0) {
                *(float4*)&s_vec[pi * 64 + crow] = make_float4(fo[0], fo[1], fo[2], fo[3]);
                short4v fb;
                fb[0] = f2bf(fo[0]); fb[1] = f2bf(fo[1]);
                fb[2] = f2bf(fo[2]); fb[3] = f2bf(fo[3]);
                *(short4v*)&s_vecbf[pi * SFB + crow] = fb;
            }
        }
        __syncthreads();   // bar3: fout ready

        // ---- FFN layer 1 via MFMA: M=16 (wave ch), K=64, N=16 (4 used) ----
        {
            const short8v vb0 = *(const short8v*)&s_vecbf[l15 * SFB + quad * 8];
            const short8v vb1 = *(const short8v*)&s_vecbf[l15 * SFB + 32 + quad * 8];
            floatx4 d = {0.f, 0.f, 0.f, 0.f};
            d = __builtin_amdgcn_mfma_f32_16x16x32_bf16(wf1_f[0], vb0, d, 0, 0, 0);
            d = __builtin_amdgcn_mfma_f32_16x16x32_bf16(wf1_f[1], vb1, d, 0, 0, 0);
            if (l15 < PTS) {
                short4v hb;
                hb[0] = f2bf(fmaxf(d[0] + bf1v.x, 0.f));
                hb[1] = f2bf(fmaxf(d[1] + bf1v.y, 0.f));
                hb[2] = f2bf(fmaxf(d[2] + bf1v.z, 0.f));
                hb[3] = f2bf(fmaxf(d[3] + bf1v.w, 0.f));
                *(short4v*)&s_hbf[l15 * SFB + crow] = hb;
            }
        }
        __syncthreads();   // bar4: h ready

        // ---- FFN layer 2 via MFMA + residual + relu, store ----
        {
            const short8v hb0 = *(const short8v*)&s_hbf[l15 * SFB + quad * 8];
            const short8v hb1 = *(const short8v*)&s_hbf[l15 * SFB + 32 + quad * 8];
            floatx4 d = {0.f, 0.f, 0.f, 0.f};
            d = __builtin_amdgcn_mfma_f32_16x16x32_bf16(wf2_f[0], hb0, d, 0, 0, 0);
            d = __builtin_amdgcn_mfma_f32_16x16x32_bf16(wf2_f[1], hb1, d, 0, 0, 0);
            if (l15 < PTS) {
                const int n = (pt0 + l15) & (N_ - 1);
                out[((size_t)(bb * 64 + crow + 0)) * N_ + n] =
                    fmaxf(d[0] + bf2v.x + s_vec[l15 * 64 + crow + 0], 0.f);
                out[((size_t)(bb * 64 + crow + 1)) * N_ + n] =
                    fmaxf(d[1] + bf2v.y + s_vec[l15 * 64 + crow + 1], 0.f);
                out[((size_t)(bb * 64 + crow + 2)) * N_ + n] =
                    fmaxf(d[2] + bf2v.z + s_vec[l15 * 64 + crow + 2], 0.f);
                out[((size_t)(bb * 64 + crow + 3)) * N_ + n] =
                    fmaxf(d[3] + bf2v.w + s_vec[l15 * 64 + crow + 3], 0.f);
            }
        }
        // hazard audit: next gather's s_fj writes separated from this iter's
        // s_fj reads by bar2..bar4; s_vecbf rewrite (next softmax) is after
        // next bar2 > this FFN1 reads; s_hbf rewrite after next bar3 > this
        // FFN2 reads. No trailing barrier needed.
    }
}

extern "C" void kernel_launch(void* const* d_in, const int* in_sizes, int n_in,
                              void* d_out, int out_size, void* d_ws, size_t ws_size,
                              hipStream_t stream)
{
    const float* p      = (const float*)d_in[0];
    const float* f      = (const float*)d_in[1];
    const float* w_attn = (const float*)d_in[2];
    const float* b_attn = (const float*)d_in[3];
    const float* w1     = (const float*)d_in[4];
    const float* b1     = (const float*)d_in[5];
    const float* w2     = (const float*)d_in[6];
    const float* b2     = (const float*)d_in[7];
    const float* wf1    = (const float*)d_in[8];
    const float* bf1    = (const float*)d_in[9];
    const float* wf2    = (const float*)d_in[10];
    const float* bf2    = (const float*)d_in[11];
    float* out = (float*)d_out;

    unsigned short* idx = (unsigned short*)d_ws;                             // 2 MB
    unsigned short* ftb = (unsigned short*)((char*)d_ws + 2u * 1024 * 1024); // 4 MB
    float4* p4          = (float4*)((char*)d_ws + 6u * 1024 * 1024);         // 512 KB

    prep_kernel<<<B_ * (N_ / 64), 256, 0, stream>>>(p, f, ftb, p4, out);
    // 32768 queries / 4 per wave / 4 waves per block = 2048 blocks
    ball_query_kernel<<<(B_ * N_) / 16, 256, 0, stream>>>(p4, idx);
    lpa_mfma_kernel<<<(B_ * N_) / (PTS * ITERS), 256, 0, stream>>>(
        p4, f, ftb, w_attn, b_attn, w1, b1, w2, b2, wf1, bf1, wf2, bf2,
        idx, out + (size_t)B_ * N_ * 3);
}